// Round 4
// baseline (6549.510 us; speedup 1.0000x reference)
//
#include <hip/hip_runtime.h>

#define T_SEQ 512
#define NBATCH 2048
#define HID 64
#define NIN 20
#define OUT_N 5

__device__ __forceinline__ float rlane(float v, int k) {
  return __uint_as_float((unsigned)__builtin_amdgcn_readlane((int)__float_as_uint(v), k));
}
__device__ __forceinline__ float sigm(float v) {
  return __builtin_amdgcn_rcpf(1.0f + __expf(-v));
}
__device__ __forceinline__ float ftanh(float v) {
  const float a = fabsf(v);
  const float e = __expf(-2.0f * a);
  return copysignf((1.0f - e) * __builtin_amdgcn_rcpf(1.0f + e), v);
}

// Fused 2-layer LSTM + projection.
// Block = 4 waves = 2 batch-groups x 2 gate-pairs; each batch-group = 4 batches.
// Wave (bg, gp) computes gates {2gp, 2gp+1} (rows: gate*64+lane) for its 4
// batches -> per-lane weights = 2*(20+64) + 2*(64+64) = 424 VGPRs, pinned
// resident via asm (R3 showed the allocator remats weight loads otherwise;
// VGPR_Count was 128, doubling issue cycles). __launch_bounds__(256,1) grants
// the 512-VGPR budget; grid = 256 blocks = exactly 1 block/CU resident.
// h broadcast via v_readlane (VALU); readlane replication is 2x (was 4x).
// Pointwise de-replicated: wave gp updates batches {2gp, 2gp+1} of its group,
// exchanging gates/h through conflict-free b32 LDS; 3 barriers per timestep.
// x rows are wave-uniform addresses -> scalar s_load (no VALU/LDS cost).
__global__ __launch_bounds__(256, 1) void lstm_fused(
    const float* __restrict__ x,
    const float* __restrict__ w_ih0, const float* __restrict__ w_hh0,
    const float* __restrict__ b_ih0, const float* __restrict__ b_hh0,
    const float* __restrict__ w_ih1, const float* __restrict__ w_hh1,
    const float* __restrict__ b_ih1, const float* __restrict__ b_hh1,
    const float* __restrict__ w_out, const float* __restrict__ b_out,
    float* __restrict__ out) {
  __shared__ float sh_gA[2][4][4][HID];  // layer0 gate exchange [bg][b][gate][u]
  __shared__ float sh_gB[2][4][4][HID];  // layer1 gate exchange
  __shared__ float sh_h0[2][4][HID];     // h0(t) exchange
  __shared__ float sh_h1[2][4][HID];     // h1(t) exchange

  const int tid = threadIdx.x;
  const int lane = tid & 63;
  const int w = __builtin_amdgcn_readfirstlane(tid >> 6);
  const int gp = w & 1;   // gate pair: gates {2gp, 2gp+1} (order i,f,g,o)
  const int bg = w >> 1;  // batch subgroup
  const int bbase = blockIdx.x * 8 + bg * 4;
  const int nb0 = 2 - gp * 2, nb1 = 3 - gp * 2;  // non-owned batches (pointwise)

  // ---- register-resident weights (pinned) ----
  float wi0[2][NIN], wh0[2][HID], wi1[2][HID], wh1[2][HID], bias0[2], bias1[2];
#pragma unroll
  for (int gi = 0; gi < 2; ++gi) {
    const int row = (gp * 2 + gi) * HID + lane;
    const float* p0 = w_ih0 + row * NIN;
#pragma unroll
    for (int k = 0; k < NIN; ++k) { wi0[gi][k] = p0[k]; asm volatile("" : "+v"(wi0[gi][k])); }
    const float* p1 = w_hh0 + row * HID;
#pragma unroll
    for (int k = 0; k < HID; ++k) { wh0[gi][k] = p1[k]; asm volatile("" : "+v"(wh0[gi][k])); }
    const float* p2 = w_ih1 + row * HID;
#pragma unroll
    for (int k = 0; k < HID; ++k) { wi1[gi][k] = p2[k]; asm volatile("" : "+v"(wi1[gi][k])); }
    const float* p3 = w_hh1 + row * HID;
#pragma unroll
    for (int k = 0; k < HID; ++k) { wh1[gi][k] = p3[k]; asm volatile("" : "+v"(wh1[gi][k])); }
    bias0[gi] = b_ih0[row] + b_hh0[row];
    bias1[gi] = b_ih1[row] + b_hh1[row];
  }

  // ---- state: lane u holds h of unit u for 4 batches; c only for owned ----
  float h0r[4], h1r[4], c0o[2], c1o[2];
#pragma unroll
  for (int b = 0; b < 4; ++b) { h0r[b] = 0.f; h1r[b] = 0.f; }
  c0o[0] = c0o[1] = c1o[0] = c1o[1] = 0.f;
  sh_h1[bg][gp * 2 + 0][lane] = 0.f;  // so the t=0 post-B2 read is valid
  sh_h1[bg][gp * 2 + 1][lane] = 0.f;
  __syncthreads();

#pragma unroll 1
  for (int t = 0; t < T_SEQ; ++t) {
    // ================= layer 0 gates =================
    float a[4][2];
#pragma unroll
    for (int b = 0; b < 4; ++b) { a[b][0] = bias0[0]; a[b][1] = bias0[1]; }
    // x part: wave-uniform address -> s_load; x value is a scalar fma operand
#pragma unroll
    for (int b = 0; b < 4; ++b) {
      const float* xb = x + ((size_t)(bbase + b) * T_SEQ + t) * NIN;
#pragma unroll
      for (int k = 0; k < NIN; ++k) {
        const float xv = xb[k];
        a[b][0] = fmaf(wi0[0][k], xv, a[b][0]);
        a[b][1] = fmaf(wi0[1][k], xv, a[b][1]);
      }
    }
    // h part: readlane broadcast
#pragma unroll
    for (int k = 0; k < HID; ++k) {
#pragma unroll
      for (int b = 0; b < 4; ++b) {
        const float hk = rlane(h0r[b], k);
        a[b][0] = fmaf(wh0[0][k], hk, a[b][0]);
        a[b][1] = fmaf(wh0[1][k], hk, a[b][1]);
      }
    }
    sh_gA[bg][nb0][gp * 2 + 0][lane] = a[nb0][0];
    sh_gA[bg][nb0][gp * 2 + 1][lane] = a[nb0][1];
    sh_gA[bg][nb1][gp * 2 + 0][lane] = a[nb1][0];
    sh_gA[bg][nb1][gp * 2 + 1][lane] = a[nb1][1];
    __syncthreads();  // B1: layer0 gates ready

    // ---- layer0 pointwise (owned batches only) ----
#pragma unroll
    for (int i = 0; i < 2; ++i) {
      const int ob = gp * 2 + i;
      float giv, gfv, ggv, gov;
      if (gp == 0) {
        giv = a[ob][0]; gfv = a[ob][1];
        ggv = sh_gA[bg][ob][2][lane]; gov = sh_gA[bg][ob][3][lane];
      } else {
        giv = sh_gA[bg][ob][0][lane]; gfv = sh_gA[bg][ob][1][lane];
        ggv = a[ob][0]; gov = a[ob][1];
      }
      const float iv = sigm(giv), fv = sigm(gfv), gv = ftanh(ggv), ov = sigm(gov);
      c0o[i] = fv * c0o[i] + iv * gv;
      const float h = ov * ftanh(c0o[i]);
      h0r[ob] = h;
      sh_h0[bg][ob][lane] = h;
    }
    __syncthreads();  // B2: h0(t) ready
    h0r[nb0] = sh_h0[bg][nb0][lane];
    h0r[nb1] = sh_h0[bg][nb1][lane];
    h1r[nb0] = sh_h1[bg][nb0][lane];  // h1(t-1) of non-owned batches
    h1r[nb1] = sh_h1[bg][nb1][lane];

    // ================= layer 1 gates =================
#pragma unroll
    for (int b = 0; b < 4; ++b) { a[b][0] = bias1[0]; a[b][1] = bias1[1]; }
#pragma unroll
    for (int k = 0; k < HID; ++k) {
#pragma unroll
      for (int b = 0; b < 4; ++b) {
        const float yk = rlane(h0r[b], k);
        const float hk = rlane(h1r[b], k);
        a[b][0] = fmaf(wi1[0][k], yk, a[b][0]);
        a[b][1] = fmaf(wi1[1][k], yk, a[b][1]);
        a[b][0] = fmaf(wh1[0][k], hk, a[b][0]);
        a[b][1] = fmaf(wh1[1][k], hk, a[b][1]);
      }
    }
    sh_gB[bg][nb0][gp * 2 + 0][lane] = a[nb0][0];
    sh_gB[bg][nb0][gp * 2 + 1][lane] = a[nb0][1];
    sh_gB[bg][nb1][gp * 2 + 0][lane] = a[nb1][0];
    sh_gB[bg][nb1][gp * 2 + 1][lane] = a[nb1][1];
    __syncthreads();  // B3: layer1 gates ready

    // ---- layer1 pointwise (owned batches only) ----
#pragma unroll
    for (int i = 0; i < 2; ++i) {
      const int ob = gp * 2 + i;
      float giv, gfv, ggv, gov;
      if (gp == 0) {
        giv = a[ob][0]; gfv = a[ob][1];
        ggv = sh_gB[bg][ob][2][lane]; gov = sh_gB[bg][ob][3][lane];
      } else {
        giv = sh_gB[bg][ob][0][lane]; gfv = sh_gB[bg][ob][1][lane];
        ggv = a[ob][0]; gov = a[ob][1];
      }
      const float iv = sigm(giv), fv = sigm(gfv), gv = ftanh(ggv), ov = sigm(gov);
      c1o[i] = fv * c1o[i] + iv * gv;
      const float h = ov * ftanh(c1o[i]);
      h1r[ob] = h;
      sh_h1[bg][ob][lane] = h;  // consumed after B2 of t+1 — race-free
    }
  }

  // ---- fused projection for owned batches ----
#pragma unroll
  for (int i = 0; i < 2; ++i) {
    const int ob = gp * 2 + i;
#pragma unroll
    for (int j = 0; j < OUT_N; ++j) {
      float p = w_out[j * HID + lane] * h1r[ob];
#pragma unroll
      for (int m = 32; m >= 1; m >>= 1) p += __shfl_xor(p, m, 64);
      if (lane == 0) out[(size_t)(bbase + ob) * OUT_N + j] = p + b_out[j];
    }
  }
}

extern "C" void kernel_launch(void* const* d_in, const int* in_sizes, int n_in,
                              void* d_out, int out_size, void* d_ws, size_t ws_size,
                              hipStream_t stream) {
  const float* x = (const float*)d_in[0];
  const float* w_ih0 = (const float*)d_in[1];
  const float* w_hh0 = (const float*)d_in[2];
  const float* b_ih0 = (const float*)d_in[3];
  const float* b_hh0 = (const float*)d_in[4];
  const float* w_ih1 = (const float*)d_in[5];
  const float* w_hh1 = (const float*)d_in[6];
  const float* b_ih1 = (const float*)d_in[7];
  const float* b_hh1 = (const float*)d_in[8];
  const float* w_out = (const float*)d_in[9];
  const float* b_out = (const float*)d_in[10];
  float* out = (float*)d_out;

  hipLaunchKernelGGL(lstm_fused, dim3(NBATCH / 8), dim3(256), 0, stream,
                     x, w_ih0, w_hh0, b_ih0, b_hh0,
                     w_ih1, w_hh1, b_ih1, b_hh1, w_out, b_out, out);
}

// Round 5
// 4192.654 us; speedup vs baseline: 1.5621x; 1.5621x over previous
//
#include <hip/hip_runtime.h>

#define T_SEQ 512
#define NBATCH 2048
#define HID 64
#define NIN 20
#define OUT_N 5
#define RB 4  // batches per block (one per wave for pointwise; replicated state)

__device__ __forceinline__ float rlane(float v, int k) {
  return __uint_as_float((unsigned)__builtin_amdgcn_readlane((int)__float_as_uint(v), k));
}
__device__ __forceinline__ float sigm(float v) {
  return __builtin_amdgcn_rcpf(1.0f + __expf(-v));
}
__device__ __forceinline__ float ftanh(float v) {
  const float a = fabsf(v);
  const float e = __expf(-2.0f * a);
  return copysignf((1.0f - e) * __builtin_amdgcn_rcpf(1.0f + e), v);
}

// Fused 2-layer LSTM + projection. R3 structure + forced weight residency.
// Block = 4 waves; wave g owns gate g (row = g*64+lane) for 4 batches.
// Per-lane register weights: wh0(64) + wi1(64) + wh1(64) = 192, PINNED via asm
// (R3: allocator rematerialized them -> per-use reloads; R4: 424 pinned went
// over the 256 arch-VGPR cap -> scratch spill. 192+~40 fits under 256.)
// wi0 lives in LDS [k][gate][unit] (stride-1 b32 reads, 2-way = free) to save
// 20 VGPRs. x rows are wave-uniform addresses -> s_load (scalar pipe).
// h broadcast via v_readlane; h/c state replicated per wave; 2 barriers/t.
__global__ __launch_bounds__(256, 2) void lstm_fused(
    const float* __restrict__ x,
    const float* __restrict__ w_ih0, const float* __restrict__ w_hh0,
    const float* __restrict__ b_ih0, const float* __restrict__ b_hh0,
    const float* __restrict__ w_ih1, const float* __restrict__ w_hh1,
    const float* __restrict__ b_ih1, const float* __restrict__ b_hh1,
    const float* __restrict__ w_out, const float* __restrict__ b_out,
    float* __restrict__ out) {
  __shared__ float wi0_lds[NIN * 4 * HID];  // [k][gate][unit], 20 KB
  __shared__ float sh_gA[RB * 4 * HID];     // layer0 gates [b][gate][u], 4 KB
  __shared__ float sh_gB[RB * 4 * HID];     // layer1 gates, 4 KB

  const int tid = threadIdx.x;
  const int lane = tid & 63;
  const int g = __builtin_amdgcn_readfirstlane(tid >> 6);  // wave id == gate id (i,f,g,o)
  const int bbase = blockIdx.x * RB;
  const int row = g * HID + lane;

  // ---- wi0 -> LDS (one-time transpose load) ----
  for (int e = tid; e < NIN * 4 * HID; e += 256) {
    const int u = e & 63;
    const int gg = (e >> 6) & 3;
    const int k = e >> 8;
    wi0_lds[e] = w_ih0[(gg * HID + u) * NIN + k];
  }

  // ---- register-resident recurrent weights (pinned) ----
  float wh0[HID], wi1[HID], wh1[HID];
  {
    const float* p = w_hh0 + row * HID;
#pragma unroll
    for (int k = 0; k < HID; ++k) { wh0[k] = p[k]; asm volatile("" : "+v"(wh0[k])); }
  }
  {
    const float* p = w_ih1 + row * HID;
#pragma unroll
    for (int k = 0; k < HID; ++k) { wi1[k] = p[k]; asm volatile("" : "+v"(wi1[k])); }
  }
  {
    const float* p = w_hh1 + row * HID;
#pragma unroll
    for (int k = 0; k < HID; ++k) { wh1[k] = p[k]; asm volatile("" : "+v"(wh1[k])); }
  }
  const float bias0 = b_ih0[row] + b_hh0[row];
  const float bias1 = b_ih1[row] + b_hh1[row];

  // ---- replicated state: lane u holds (h,c) of unit u for RB batches ----
  float h0r[RB], c0r[RB], h1r[RB], c1r[RB];
#pragma unroll
  for (int b = 0; b < RB; ++b) h0r[b] = c0r[b] = h1r[b] = c1r[b] = 0.0f;
  __syncthreads();  // wi0_lds ready

#pragma unroll 1
  for (int t = 0; t < T_SEQ; ++t) {
    // ================= layer 0 gates =================
    float a[RB];
#pragma unroll
    for (int b = 0; b < RB; ++b) a[b] = bias0;
    // x part: wi0 from LDS (1 read / k, reused over 4 batches); x via s_load
#pragma unroll
    for (int k = 0; k < NIN; ++k) {
      const float wl = wi0_lds[(k * 4 + g) * HID + lane];
#pragma unroll
      for (int b = 0; b < RB; ++b) {
        const float xv = x[((size_t)(bbase + b) * T_SEQ + t) * NIN + k];
        a[b] = fmaf(wl, xv, a[b]);
      }
    }
    // h part: readlane broadcast (VALU pipe)
#pragma unroll
    for (int k = 0; k < HID; ++k) {
#pragma unroll
      for (int b = 0; b < RB; ++b) a[b] = fmaf(wh0[k], rlane(h0r[b], k), a[b]);
    }
#pragma unroll
    for (int b = 0; b < RB; ++b) sh_gA[(b * 4 + g) * HID + lane] = a[b];
    __syncthreads();  // B1

    // ---- layer0 pointwise, replicated (unit = lane) ----
#pragma unroll
    for (int b = 0; b < RB; ++b) {
      const float iv = sigm(sh_gA[(b * 4 + 0) * HID + lane]);
      const float fv = sigm(sh_gA[(b * 4 + 1) * HID + lane]);
      const float gv = ftanh(sh_gA[(b * 4 + 2) * HID + lane]);
      const float ov = sigm(sh_gA[(b * 4 + 3) * HID + lane]);
      c0r[b] = fv * c0r[b] + iv * gv;
      h0r[b] = ov * ftanh(c0r[b]);
    }

    // ================= layer 1 gates =================
#pragma unroll
    for (int b = 0; b < RB; ++b) a[b] = bias1;
#pragma unroll
    for (int k = 0; k < HID; ++k) {
#pragma unroll
      for (int b = 0; b < RB; ++b) {
        a[b] = fmaf(wi1[k], rlane(h0r[b], k), a[b]);  // input = h0(t)
        a[b] = fmaf(wh1[k], rlane(h1r[b], k), a[b]);  // recurrent h1(t-1)
      }
    }
#pragma unroll
    for (int b = 0; b < RB; ++b) sh_gB[(b * 4 + g) * HID + lane] = a[b];
    __syncthreads();  // B2

    // ---- layer1 pointwise, replicated ----
#pragma unroll
    for (int b = 0; b < RB; ++b) {
      const float iv = sigm(sh_gB[(b * 4 + 0) * HID + lane]);
      const float fv = sigm(sh_gB[(b * 4 + 1) * HID + lane]);
      const float gv = ftanh(sh_gB[(b * 4 + 2) * HID + lane]);
      const float ov = sigm(sh_gB[(b * 4 + 3) * HID + lane]);
      c1r[b] = fv * c1r[b] + iv * gv;
      h1r[b] = ov * ftanh(c1r[b]);
    }
  }

  // ---- fused projection: out[b] = h1 @ w_out^T + b_out (wave 0 only) ----
  if (g == 0) {
#pragma unroll
    for (int b = 0; b < RB; ++b) {
#pragma unroll
      for (int j = 0; j < OUT_N; ++j) {
        float p = w_out[j * HID + lane] * h1r[b];
#pragma unroll
        for (int m = 32; m >= 1; m >>= 1) p += __shfl_xor(p, m, 64);
        if (lane == 0) out[(size_t)(bbase + b) * OUT_N + j] = p + b_out[j];
      }
    }
  }
}

extern "C" void kernel_launch(void* const* d_in, const int* in_sizes, int n_in,
                              void* d_out, int out_size, void* d_ws, size_t ws_size,
                              hipStream_t stream) {
  const float* x = (const float*)d_in[0];
  const float* w_ih0 = (const float*)d_in[1];
  const float* w_hh0 = (const float*)d_in[2];
  const float* b_ih0 = (const float*)d_in[3];
  const float* b_hh0 = (const float*)d_in[4];
  const float* w_ih1 = (const float*)d_in[5];
  const float* w_hh1 = (const float*)d_in[6];
  const float* b_ih1 = (const float*)d_in[7];
  const float* b_hh1 = (const float*)d_in[8];
  const float* w_out = (const float*)d_in[9];
  const float* b_out = (const float*)d_in[10];
  float* out = (float*)d_out;

  hipLaunchKernelGGL(lstm_fused, dim3(NBATCH / RB), dim3(256), 0, stream,
                     x, w_ih0, w_hh0, b_ih0, b_hh0,
                     w_ih1, w_hh1, b_ih1, b_hh1, w_out, b_out, out);
}

// Round 6
// 1203.058 us; speedup vs baseline: 5.4441x; 3.4850x over previous
//
#include <hip/hip_runtime.h>

#define T_SEQ 512
#define HID 64
#define NIN 20
#define OUT_N 5

typedef float f32x4 __attribute__((ext_vector_type(4)));
typedef int v4i __attribute__((ext_vector_type(4)));

// D = A*B + D, A from AGPR (keeps the 224-reg weight set out of the arch-VGPR
// budget; MFMA reads AGPR operands natively on gfx950 unified file).
#define MFMA(acc, A, B) \
  asm("v_mfma_f32_16x16x32_bf16 %0, %1, %2, %0" : "+v"(acc) : "a"(A), "v"(B))

__device__ __forceinline__ unsigned bf16_rne(float f) {
  unsigned u = __float_as_uint(f);
  return (u + 0x7fffu + ((u >> 16) & 1u)) >> 16;
}
__device__ __forceinline__ void bf16_split(float f, unsigned &hb, unsigned &lb) {
  hb = bf16_rne(f);
  lb = bf16_rne(f - __uint_as_float(hb << 16));
}
// 8 floats (k = 0..7 consecutive) -> bf16x8 hi-frag and lo-frag (A/B operand regs)
__device__ __forceinline__ void pack_frags(const float* v, v4i &hi, v4i &lo) {
#pragma unroll
  for (int d = 0; d < 4; ++d) {
    unsigned h0, l0, h1, l1;
    bf16_split(v[2 * d], h0, l0);
    bf16_split(v[2 * d + 1], h1, l1);
    hi[d] = (int)((h1 << 16) | h0);
    lo[d] = (int)((l1 << 16) | l0);
  }
}
__device__ __forceinline__ float sigm(float v) { return __builtin_amdgcn_rcpf(1.f + __expf(-v)); }
__device__ __forceinline__ float ftanh(float v) {
  float a = fabsf(v), e = __expf(-2.f * a);
  return copysignf((1.f - e) * __builtin_amdgcn_rcpf(1.f + e), v);
}

// Unpack 8 packed (lo16|hi16) u32 from LDS h-buffer into B-operand hi/lo frags.
// B-frag layout (16x16x32): lane holds B[k = 8*(lane>>4) + j][n = lane&15].
__device__ __forceinline__ void unpack_frags(const unsigned* buf, int kt, int q, int n16,
                                             v4i &hi, v4i &lo) {
  const int base = (32 * kt + 8 * q) * 17 + n16;
  unsigned p[8];
#pragma unroll
  for (int j = 0; j < 8; ++j) p[j] = buf[base + 17 * j];  // ds_read2-mergeable
#pragma unroll
  for (int d = 0; d < 4; ++d) {
    hi[d] = (int)((p[2 * d + 1] << 16) | (p[2 * d] & 0xffffu));
    lo[d] = (int)((p[2 * d + 1] & 0xffff0000u) | (p[2 * d] >> 16));
  }
}

// Split pointwise: lanes n<8 handle D-rows r=0,1; lanes n>=8 take r=2,3 of the
// partner lane (shfl_xor 8) -> halves the transcendental chain per lane.
__device__ __forceinline__ void pointwise(const f32x4* acc, int grp, float &ca, float &cb,
                                          unsigned &pka, unsigned &pkb) {
  float s[4][2];
#pragma unroll
  for (int g = 0; g < 4; ++g) {
    float z = __shfl_xor(acc[g][2], 8);
    float w = __shfl_xor(acc[g][3], 8);
    s[g][0] = grp ? z : acc[g][0];
    s[g][1] = grp ? w : acc[g][1];
  }
#pragma unroll
  for (int v = 0; v < 2; ++v) {
    const float iv = sigm(s[0][v]), fv = sigm(s[1][v]);
    const float gv = ftanh(s[2][v]), ov = sigm(s[3][v]);
    float &c = v ? cb : ca;
    c = fv * c + iv * gv;
    const float h = ov * ftanh(c);
    unsigned hb, lb;
    bf16_split(h, hb, lb);
    (v ? pkb : pka) = (lb << 16) | hb;
  }
}

// Fused 2-layer LSTM + projection on the matrix pipe.
// Block = 4 waves, 8 batches/block, grid 256 (1 block/CU). Wave w owns units
// [16w,16w+16) for all 4 gates: MFMA D-layout (row=4q+r, col=n) aligns i/f/g/o
// accs per (unit,batch) -> in-register pointwise. fp32 via bf16 hi/lo 3-product.
// h exchanged via packed-u32 LDS (pad 17, 2-way conflicts = free), parity
// double-buffered, ONE barrier per timestep (hazards separated by B1(t)/B1(t+1)).
__global__ __launch_bounds__(256, 1) void lstm_mfma(
    const float* __restrict__ x,
    const float* __restrict__ w_ih0, const float* __restrict__ w_hh0,
    const float* __restrict__ b_ih0, const float* __restrict__ b_hh0,
    const float* __restrict__ w_ih1, const float* __restrict__ w_hh1,
    const float* __restrict__ b_ih1, const float* __restrict__ b_hh1,
    const float* __restrict__ w_out, const float* __restrict__ b_out,
    float* __restrict__ out) {
  __shared__ unsigned hpk0[2][64 * 17];  // h0, packed (lo16|hi16), [unit][batch(+pad)]
  __shared__ unsigned hpk1[2][64 * 17];  // h1

  const int tid = threadIdx.x;
  const int lane = tid & 63;
  const int w = __builtin_amdgcn_readfirstlane(tid >> 6);  // unit group
  const int q = lane >> 4;
  const int n16 = lane & 15;  // tile column (batch slot; valid < 8)
  const int nb = lane & 7;
  const int grp = (lane >> 3) & 1;
  const int blk = blockIdx.x;

  for (int e = tid; e < 64 * 17; e += 256) { hpk0[0][e] = 0u; hpk1[0][e] = 0u; }

  // ---- weight A-frags -> AGPRs. A-layout: lane holds A[m=lane&15][k=8q+j]. ----
  v4i a0x[4][2];      // [gate][hi/lo]  W_ih0, K=32 (cols >= 20 zero)
  v4i a0h[4][2][2];   // [gate][kt][hi/lo]  W_hh0
  v4i a1y[4][2][2];   // W_ih1 (input = h0)
  v4i a1h[4][2][2];   // W_hh1
  {
    float vv[8];
#pragma unroll
    for (int g = 0; g < 4; ++g) {
      const int row = g * HID + 16 * w + n16;
#pragma unroll
      for (int j = 0; j < 8; ++j) {
        const int k = 8 * q + j;
        vv[j] = (k < NIN) ? w_ih0[row * NIN + k] : 0.f;
      }
      pack_frags(vv, a0x[g][0], a0x[g][1]);
#pragma unroll
      for (int kt = 0; kt < 2; ++kt) {
#pragma unroll
        for (int j = 0; j < 8; ++j) vv[j] = w_hh0[row * HID + 32 * kt + 8 * q + j];
        pack_frags(vv, a0h[g][kt][0], a0h[g][kt][1]);
#pragma unroll
        for (int j = 0; j < 8; ++j) vv[j] = w_ih1[row * HID + 32 * kt + 8 * q + j];
        pack_frags(vv, a1y[g][kt][0], a1y[g][kt][1]);
#pragma unroll
        for (int j = 0; j < 8; ++j) vv[j] = w_hh1[row * HID + 32 * kt + 8 * q + j];
        pack_frags(vv, a1h[g][kt][0], a1h[g][kt][1]);
      }
    }
  }

  // ---- bias in D-layout: lane's D rows are m = 4q + r ----
  f32x4 bias0f[4], bias1f[4];
#pragma unroll
  for (int g = 0; g < 4; ++g)
#pragma unroll
    for (int r = 0; r < 4; ++r) {
      const int row = g * HID + 16 * w + 4 * q + r;
      bias0f[g][r] = b_ih0[row] + b_hh0[row];
      bias1f[g][r] = b_ih1[row] + b_hh1[row];
    }

  // ---- x: per-lane streamed offsets (B-frag: k = 8q+j, batch = n16, clamped) ----
  unsigned xoff[8];
#pragma unroll
  for (int j = 0; j < 8; ++j) {
    const int k = 8 * q + j;
    xoff[j] = (unsigned)((((blk * 8 + nb) * T_SEQ) * NIN + (k < NIN ? k : 0)) * 4);
  }
  v4i xmask;
#pragma unroll
  for (int d = 0; d < 4; ++d) {
    const unsigned m0 = (8 * q + 2 * d < NIN) ? 0x0000ffffu : 0u;
    const unsigned m1 = (8 * q + 2 * d + 1 < NIN) ? 0xffff0000u : 0u;
    xmask[d] = (int)(m0 | m1);
  }

  // producer LDS write slots (this lane updates units u0, u0+1 for batch nb)
  const int u0 = 16 * w + 4 * q + 2 * grp;
  const int widx = u0 * 17 + nb;

  float c0a = 0.f, c0b = 0.f, c1a = 0.f, c1b = 0.f;
  v4i h0f[2][2], h1f[2][2];
#pragma unroll
  for (int kt = 0; kt < 2; ++kt)
#pragma unroll
    for (int hl = 0; hl < 2; ++hl) {
      h0f[kt][hl][0] = 0; h0f[kt][hl][1] = 0; h0f[kt][hl][2] = 0; h0f[kt][hl][3] = 0;
    }

  float xv[8];
#pragma unroll
  for (int j = 0; j < 8; ++j) xv[j] = *(const float*)((const char*)x + xoff[j]);
#pragma unroll
  for (int j = 0; j < 8; ++j) xoff[j] += NIN * 4;

  __syncthreads();  // LDS zero-init visible

#pragma unroll 1
  for (int t = 0; t < T_SEQ; ++t) {
    const int pr = t & 1, pw = pr ^ 1;

    // x(t) frags
    v4i xhi, xlo;
    pack_frags(xv, xhi, xlo);
#pragma unroll
    for (int d = 0; d < 4; ++d) { xhi[d] &= xmask[d]; xlo[d] &= xmask[d]; }

    // prefetch x(t+1) early — latency spans the whole iteration
    float xn[8];
    if (t < T_SEQ - 1) {
#pragma unroll
      for (int j = 0; j < 8; ++j) xn[j] = *(const float*)((const char*)x + xoff[j]);
#pragma unroll
      for (int j = 0; j < 8; ++j) xoff[j] += NIN * 4;
    }

    // ================= layer 0: gates = b + Wx·x + Wh·h0(t-1) =================
    f32x4 acc[4];
#pragma unroll
    for (int g = 0; g < 4; ++g) acc[g] = bias0f[g];
#pragma unroll
    for (int g = 0; g < 4; ++g) {
      MFMA(acc[g], a0x[g][0], xhi);
      MFMA(acc[g], a0x[g][0], xlo);
      MFMA(acc[g], a0x[g][1], xhi);
    }
#pragma unroll
    for (int kt = 0; kt < 2; ++kt)
#pragma unroll
      for (int g = 0; g < 4; ++g) {
        MFMA(acc[g], a0h[g][kt][0], h0f[kt][0]);
        MFMA(acc[g], a0h[g][kt][0], h0f[kt][1]);
        MFMA(acc[g], a0h[g][kt][1], h0f[kt][0]);
      }

    // layer0 pointwise -> write h0(t) packed into hpk0[pw]
    {
      unsigned pka, pkb;
      pointwise(acc, grp, c0a, c0b, pka, pkb);
      hpk0[pw][widx] = pka;
      hpk0[pw][widx + 17] = pkb;
    }
    __syncthreads();  // B1: h0(t) ready; h1(t-1) from previous iter also ready

    // refresh B-frags: y = h0(t) (reused as h0 recurrent next iter), h1(t-1)
#pragma unroll
    for (int kt = 0; kt < 2; ++kt) {
      unpack_frags(hpk0[pw], kt, q, n16, h0f[kt][0], h0f[kt][1]);
      unpack_frags(hpk1[pr], kt, q, n16, h1f[kt][0], h1f[kt][1]);
    }

    // ================= layer 1: gates = b + Wy·h0(t) + Wh·h1(t-1) =================
#pragma unroll
    for (int g = 0; g < 4; ++g) acc[g] = bias1f[g];
#pragma unroll
    for (int kt = 0; kt < 2; ++kt)
#pragma unroll
      for (int g = 0; g < 4; ++g) {
        MFMA(acc[g], a1y[g][kt][0], h0f[kt][0]);
        MFMA(acc[g], a1y[g][kt][0], h0f[kt][1]);
        MFMA(acc[g], a1y[g][kt][1], h0f[kt][0]);
        MFMA(acc[g], a1h[g][kt][0], h1f[kt][0]);
        MFMA(acc[g], a1h[g][kt][0], h1f[kt][1]);
        MFMA(acc[g], a1h[g][kt][1], h1f[kt][0]);
      }

    // layer1 pointwise -> write h1(t) into hpk1[pw] (read after B1 of t+1)
    {
      unsigned pka, pkb;
      pointwise(acc, grp, c1a, c1b, pka, pkb);
      hpk1[pw][widx] = pka;
      hpk1[pw][widx + 17] = pkb;
    }

    if (t < T_SEQ - 1) {
#pragma unroll
      for (int j = 0; j < 8; ++j) xv[j] = xn[j];
    }
  }

  // ---- projection: out[b] = h1(511) @ w_out^T + b_out ----
  __syncthreads();  // h1(511) in hpk1[(511+1)&1] = hpk1[0]
  if (tid < 8 * OUT_N) {
    const int b = tid / OUT_N, j = tid - b * OUT_N;
    float s = b_out[j];
    const unsigned* hb = hpk1[0];
    for (int u = 0; u < HID; ++u) {
      const unsigned pk = hb[u * 17 + b];
      const float hv = __uint_as_float(pk << 16) + __uint_as_float(pk & 0xffff0000u);
      s = fmaf(w_out[j * HID + u], hv, s);
    }
    out[(blk * 8 + b) * OUT_N + j] = s;
  }
}

extern "C" void kernel_launch(void* const* d_in, const int* in_sizes, int n_in,
                              void* d_out, int out_size, void* d_ws, size_t ws_size,
                              hipStream_t stream) {
  const float* x = (const float*)d_in[0];
  const float* w_ih0 = (const float*)d_in[1];
  const float* w_hh0 = (const float*)d_in[2];
  const float* b_ih0 = (const float*)d_in[3];
  const float* b_hh0 = (const float*)d_in[4];
  const float* w_ih1 = (const float*)d_in[5];
  const float* w_hh1 = (const float*)d_in[6];
  const float* b_ih1 = (const float*)d_in[7];
  const float* b_hh1 = (const float*)d_in[8];
  const float* w_out = (const float*)d_in[9];
  const float* b_out = (const float*)d_in[10];
  float* out = (float*)d_out;

  hipLaunchKernelGGL(lstm_mfma, dim3(2048 / 8), dim3(256), 0, stream,
                     x, w_ih0, w_hh0, b_ih0, b_hh0,
                     w_ih1, w_hh1, b_ih1, b_hh1, w_out, b_out, out);
}

// Round 7
// 964.990 us; speedup vs baseline: 6.7871x; 1.2467x over previous
//
#include <hip/hip_runtime.h>

#define T_SEQ 512
#define HID 64
#define NIN 20
#define OUT_N 5
#define UST 18  // h-buffer unit stride (pad 2): unpack banks = (16q+n16+c)%32 -> conflict-free phases

typedef float f32x4 __attribute__((ext_vector_type(4)));
typedef int v4i __attribute__((ext_vector_type(4)));

// D = A*B + D, A from AGPR (keeps weights out of the arch-VGPR budget).
#define MFMA(acc, A, B) \
  asm("v_mfma_f32_16x16x32_bf16 %0, %1, %2, %0" : "+v"(acc) : "a"(A), "v"(B))

// Weight-register overlay (layer0 waves use 24 slots, layer1 waves 32; single
// static live range keeps total regs <= 128 AGPR + ~100 VGPR < 256/wave).
#define WA_X(g, hl) wr[2 * (g) + (hl)]
#define WA_H(g, kt, hl) wr[8 + 4 * (g) + 2 * (kt) + (hl)]
#define WB_Y(g, kt, hl) wr[4 * (g) + 2 * (kt) + (hl)]
#define WB_H(g, kt, hl) wr[16 + 4 * (g) + 2 * (kt) + (hl)]

__device__ __forceinline__ unsigned bf16_rne(float f) {
  unsigned u = __float_as_uint(f);
  return (u + 0x7fffu + ((u >> 16) & 1u)) >> 16;
}
__device__ __forceinline__ void bf16_split(float f, unsigned &hb, unsigned &lb) {
  hb = bf16_rne(f);
  lb = bf16_rne(f - __uint_as_float(hb << 16));
}
__device__ __forceinline__ void pack_frags(const float* v, v4i &hi, v4i &lo) {
#pragma unroll
  for (int d = 0; d < 4; ++d) {
    unsigned h0, l0, h1, l1;
    bf16_split(v[2 * d], h0, l0);
    bf16_split(v[2 * d + 1], h1, l1);
    hi[d] = (int)((h1 << 16) | h0);
    lo[d] = (int)((l1 << 16) | l0);
  }
}
__device__ __forceinline__ float sigm(float v) { return __builtin_amdgcn_rcpf(1.f + __expf(-v)); }
__device__ __forceinline__ float ftanh(float v) {
  float a = fabsf(v), e = __expf(-2.f * a);
  return copysignf((1.f - e) * __builtin_amdgcn_rcpf(1.f + e), v);
}

// LDS h-buffer layout: word = unit*UST + batch, packed (lo16|hi16).
// B-frag (16x16x32): lane (q=lane>>4, n16=lane&15) holds B[k=8q+j][n16].
__device__ __forceinline__ void unpack_frags(const unsigned* buf, int kt, int q, int n16,
                                             v4i &hi, v4i &lo) {
  const int base = (32 * kt + 8 * q) * UST + n16;
  unsigned p[8];
#pragma unroll
  for (int j = 0; j < 8; ++j) p[j] = buf[base + UST * j];
#pragma unroll
  for (int d = 0; d < 4; ++d) {
    hi[d] = (int)((p[2 * d + 1] << 16) | (p[2 * d] & 0xffffu));
    lo[d] = (int)((p[2 * d + 1] & 0xffff0000u) | (p[2 * d] >> 16));
  }
}

// Split pointwise: lanes n16<8 do D-rows r=0,1; lanes n16>=8 take r=2,3 of the
// partner (shfl_xor 8 -> DPP row_ror, VALU pipe) for batch nb=lane&7.
__device__ __forceinline__ void pointwise(const f32x4* acc, int grp, float &ca, float &cb,
                                          unsigned &pka, unsigned &pkb) {
  float s[4][2];
#pragma unroll
  for (int g = 0; g < 4; ++g) {
    float z = __shfl_xor(acc[g][2], 8);
    float w = __shfl_xor(acc[g][3], 8);
    s[g][0] = grp ? z : acc[g][0];
    s[g][1] = grp ? w : acc[g][1];
  }
#pragma unroll
  for (int v = 0; v < 2; ++v) {
    const float iv = sigm(s[0][v]), fv = sigm(s[1][v]);
    const float gv = ftanh(s[2][v]), ov = sigm(s[3][v]);
    float &c = v ? cb : ca;
    c = fv * c + iv * gv;
    const float h = ov * ftanh(c);
    unsigned hb, lb;
    bf16_split(h, hb, lb);
    (v ? pkb : pka) = (lb << 16) | hb;
  }
}

// Layer-pipelined fused LSTM: block = 8 waves on 256 blocks = 2 waves/SIMD.
// Waves 0-3 (group A) = layer0 at time i; waves 4-7 (group B) = layer1 at time
// i-1 (h0 ring, double-buffered). Layer0's recurrence is independent of layer1,
// so both groups run concurrently with ONE barrier per iteration; MFMA/VALU/LDS
// of the paired waves co-schedule per m114. fp32 via bf16 hi/lo 3-product.
__global__ __launch_bounds__(512, 2) void lstm_pipe(
    const float* __restrict__ x,
    const float* __restrict__ w_ih0, const float* __restrict__ w_hh0,
    const float* __restrict__ b_ih0, const float* __restrict__ b_hh0,
    const float* __restrict__ w_ih1, const float* __restrict__ w_hh1,
    const float* __restrict__ b_ih1, const float* __restrict__ b_hh1,
    const float* __restrict__ w_out, const float* __restrict__ b_out,
    float* __restrict__ out) {
  __shared__ unsigned hpk0[2][64 * UST];  // h0 ring: parity i&1 holds h0(i)
  __shared__ unsigned hpk1[2][64 * UST];  // h1 ring: parity i&1 holds h1(i-1)

  const int tid = threadIdx.x;
  const int lane = tid & 63;
  const int wv = __builtin_amdgcn_readfirstlane(tid >> 6);  // 0..7
  const int isB = wv >> 2;   // 0 = layer0 group, 1 = layer1 group
  const int w = wv & 3;      // unit group [16w, 16w+16)
  const int q = lane >> 4;
  const int n16 = lane & 15;
  const int nb = lane & 7;
  const int grp = (lane >> 3) & 1;
  const int blk = blockIdx.x;

  for (int e = tid; e < 64 * UST; e += 512) {
    hpk0[0][e] = 0u; hpk0[1][e] = 0u; hpk1[0][e] = 0u; hpk1[1][e] = 0u;
  }

  // ---- weights -> AGPR overlay. A-frag layout: lane holds A[m=n16][k=8q+j]. ----
  v4i wr[32];
  f32x4 biasf[4];
  {
    float vv[8];
    if (!isB) {
#pragma unroll
      for (int g = 0; g < 4; ++g) {
        const int row = g * HID + 16 * w + n16;
#pragma unroll
        for (int j = 0; j < 8; ++j) {
          const int k = 8 * q + j;
          vv[j] = (k < NIN) ? w_ih0[row * NIN + k] : 0.f;
        }
        pack_frags(vv, WA_X(g, 0), WA_X(g, 1));
#pragma unroll
        for (int kt = 0; kt < 2; ++kt) {
#pragma unroll
          for (int j = 0; j < 8; ++j) vv[j] = w_hh0[row * HID + 32 * kt + 8 * q + j];
          pack_frags(vv, WA_H(g, kt, 0), WA_H(g, kt, 1));
        }
#pragma unroll
        for (int r = 0; r < 4; ++r) {
          const int br = g * HID + 16 * w + 4 * q + r;
          biasf[g][r] = b_ih0[br] + b_hh0[br];
        }
      }
    } else {
#pragma unroll
      for (int g = 0; g < 4; ++g) {
        const int row = g * HID + 16 * w + n16;
#pragma unroll
        for (int kt = 0; kt < 2; ++kt) {
#pragma unroll
          for (int j = 0; j < 8; ++j) vv[j] = w_ih1[row * HID + 32 * kt + 8 * q + j];
          pack_frags(vv, WB_Y(g, kt, 0), WB_Y(g, kt, 1));
#pragma unroll
          for (int j = 0; j < 8; ++j) vv[j] = w_hh1[row * HID + 32 * kt + 8 * q + j];
          pack_frags(vv, WB_H(g, kt, 0), WB_H(g, kt, 1));
        }
#pragma unroll
        for (int r = 0; r < 4; ++r) {
          const int br = g * HID + 16 * w + 4 * q + r;
          biasf[g][r] = b_ih1[br] + b_hh1[br];
        }
      }
    }
  }

  // producer slots: this lane updates units u0, u0+1 for batch nb
  const int u0 = 16 * w + 4 * q + 2 * grp;
  const int widx = u0 * UST + nb;

  float ca = 0.f, cb = 0.f;  // c-state (layer0 in A-waves, layer1 in B-waves)

  // ---- x streaming (group A only): B-frag k=8q+j, batch nb ----
  unsigned xoff[8];
  v4i xmask;
  float xv[8];
  if (!isB) {
#pragma unroll
    for (int j = 0; j < 8; ++j) {
      const int k = 8 * q + j;
      xoff[j] = (unsigned)((((blk * 8 + nb) * T_SEQ) * NIN + (k < NIN ? k : 0)) * 4);
    }
#pragma unroll
    for (int d = 0; d < 4; ++d) {
      const unsigned m0 = (8 * q + 2 * d < NIN) ? 0x0000ffffu : 0u;
      const unsigned m1 = (8 * q + 2 * d + 1 < NIN) ? 0xffff0000u : 0u;
      xmask[d] = (int)(m0 | m1);
    }
#pragma unroll
    for (int j = 0; j < 8; ++j) xv[j] = *(const float*)((const char*)x + xoff[j]);
#pragma unroll
    for (int j = 0; j < 8; ++j) xoff[j] += NIN * 4;
  }

  __syncthreads();  // LDS zero-init visible

#pragma unroll 1
  for (int i = 0; i <= T_SEQ; ++i) {
    const int par = i & 1;

    if (!isB) {
      if (i < T_SEQ) {
        // ======== layer 0, time i: gates = b + Wx·x(i) + Wh·h0(i-1) ========
        v4i xhi, xlo;
        pack_frags(xv, xhi, xlo);
#pragma unroll
        for (int d = 0; d < 4; ++d) { xhi[d] &= xmask[d]; xlo[d] &= xmask[d]; }
        float xn[8];
        if (i < T_SEQ - 1) {  // prefetch x(i+1)
#pragma unroll
          for (int j = 0; j < 8; ++j) xn[j] = *(const float*)((const char*)x + xoff[j]);
#pragma unroll
          for (int j = 0; j < 8; ++j) xoff[j] += NIN * 4;
        }
        v4i hf[2][2];
#pragma unroll
        for (int kt = 0; kt < 2; ++kt)
          unpack_frags(hpk0[par ^ 1], kt, q, n16, hf[kt][0], hf[kt][1]);

        f32x4 acc[4];
#pragma unroll
        for (int g = 0; g < 4; ++g) acc[g] = biasf[g];
#pragma unroll
        for (int g = 0; g < 4; ++g) {
          MFMA(acc[g], WA_X(g, 0), xhi);
          MFMA(acc[g], WA_X(g, 0), xlo);
          MFMA(acc[g], WA_X(g, 1), xhi);
        }
#pragma unroll
        for (int kt = 0; kt < 2; ++kt)
#pragma unroll
          for (int g = 0; g < 4; ++g) {
            MFMA(acc[g], WA_H(g, kt, 0), hf[kt][0]);
            MFMA(acc[g], WA_H(g, kt, 0), hf[kt][1]);
            MFMA(acc[g], WA_H(g, kt, 1), hf[kt][0]);
          }
        unsigned pka, pkb;
        pointwise(acc, grp, ca, cb, pka, pkb);
        hpk0[par][widx] = pka;
        hpk0[par][widx + UST] = pkb;
        if (i < T_SEQ - 1) {
#pragma unroll
          for (int j = 0; j < 8; ++j) xv[j] = xn[j];
        }
      }
    } else {
      if (i >= 1) {
        // ======== layer 1, time i-1: gates = b + Wy·h0(i-1) + Wh·h1(i-2) ========
        v4i yf[2][2], hf[2][2];
#pragma unroll
        for (int kt = 0; kt < 2; ++kt) {
          unpack_frags(hpk0[par ^ 1], kt, q, n16, yf[kt][0], yf[kt][1]);
          unpack_frags(hpk1[par ^ 1], kt, q, n16, hf[kt][0], hf[kt][1]);
        }
        f32x4 acc[4];
#pragma unroll
        for (int g = 0; g < 4; ++g) acc[g] = biasf[g];
#pragma unroll
        for (int kt = 0; kt < 2; ++kt)
#pragma unroll
          for (int g = 0; g < 4; ++g) {
            MFMA(acc[g], WB_Y(g, kt, 0), yf[kt][0]);
            MFMA(acc[g], WB_Y(g, kt, 0), yf[kt][1]);
            MFMA(acc[g], WB_Y(g, kt, 1), yf[kt][0]);
            MFMA(acc[g], WB_H(g, kt, 0), hf[kt][0]);
            MFMA(acc[g], WB_H(g, kt, 0), hf[kt][1]);
            MFMA(acc[g], WB_H(g, kt, 1), hf[kt][0]);
          }
        unsigned pka, pkb;
        pointwise(acc, grp, ca, cb, pka, pkb);
        hpk1[par][widx] = pka;
        hpk1[par][widx + UST] = pkb;
      }
    }
    __syncthreads();
  }

  // ---- projection: out[b] = h1(511) @ w_out^T + b_out; h1(511) in hpk1[0] ----
  if (tid < 8 * OUT_N) {
    const int b = tid / OUT_N, j = tid - b * OUT_N;
    float s = b_out[j];
    const unsigned* hb = hpk1[0];
    for (int u = 0; u < HID; ++u) {
      const unsigned pk = hb[u * UST + b];
      const float hv = __uint_as_float(pk << 16) + __uint_as_float(pk & 0xffff0000u);
      s = fmaf(w_out[j * HID + u], hv, s);
    }
    out[(blk * 8 + b) * OUT_N + j] = s;
  }
}

extern "C" void kernel_launch(void* const* d_in, const int* in_sizes, int n_in,
                              void* d_out, int out_size, void* d_ws, size_t ws_size,
                              hipStream_t stream) {
  const float* x = (const float*)d_in[0];
  const float* w_ih0 = (const float*)d_in[1];
  const float* w_hh0 = (const float*)d_in[2];
  const float* b_ih0 = (const float*)d_in[3];
  const float* b_hh0 = (const float*)d_in[4];
  const float* w_ih1 = (const float*)d_in[5];
  const float* w_hh1 = (const float*)d_in[6];
  const float* b_ih1 = (const float*)d_in[7];
  const float* b_hh1 = (const float*)d_in[8];
  const float* w_out = (const float*)d_in[9];
  const float* b_out = (const float*)d_in[10];
  float* out = (float*)d_out;

  hipLaunchKernelGGL(lstm_pipe, dim3(2048 / 8), dim3(512), 0, stream,
                     x, w_ih0, w_hh0, b_ih0, b_hh0,
                     w_ih1, w_hh1, b_ih1, b_hh1, w_out, b_out, out);
}